// Round 1
// baseline (698.125 us; speedup 1.0000x reference)
//
#include <hip/hip_runtime.h>
#include <hip/hip_bf16.h>
#include <math.h>

#define HID 512
#define TLEN 4096
#define BATCH 64

// ---------------------------------------------------------------------------
// K1: v[b,h] = sum_o hidden[b,o] * W[o,h]    (v = hidden @ W, [B,H])
// The softmax-invariant bias term dot(b, hidden[b]) is dropped deliberately.
// One block per b, 512 threads (one per h). W column reads are coalesced
// across threads; W (1 MB) stays L2-resident across the 64 blocks.
// ---------------------------------------------------------------------------
__global__ __launch_bounds__(HID) void proj_kernel(const float* __restrict__ hidden,
                                                   const float* __restrict__ W,
                                                   float* __restrict__ v) {
    __shared__ float hs[HID];
    const int b = blockIdx.x;
    const int h = threadIdx.x;
    hs[h] = hidden[b * HID + h];
    __syncthreads();
    float s = 0.f;
#pragma unroll 16
    for (int o = 0; o < HID; ++o) {
        s = fmaf(hs[o], W[o * HID + h], s);
    }
    v[b * HID + h] = s;
}

// ---------------------------------------------------------------------------
// K2: scores[b,t] = dot(enc[b,t,:], v[b,:])
// One wave (64 lanes) per t; lane i reads row float4 [i] and [64+i] — two
// fully-coalesced 1 KB segments per wave-load. v fragment is loop-invariant
// per lane (8 regs). Each wave iterates 16 t's; block of 4 waves covers 64 t.
// ---------------------------------------------------------------------------
__global__ __launch_bounds__(256) void score_kernel(const float* __restrict__ enc,
                                                    const float* __restrict__ v,
                                                    float* __restrict__ scores) {
    const int b    = blockIdx.y;
    const int wave = threadIdx.x >> 6;
    const int lane = threadIdx.x & 63;
    const int t0   = blockIdx.x * 64 + wave * 16;

    const float4* v4 = (const float4*)(v + b * HID);
    const float4  va = v4[lane];        // h = 4*lane .. 4*lane+3
    const float4  vb = v4[64 + lane];   // h = 256+4*lane ..

    const float4* e4 = (const float4*)(enc + (size_t)b * TLEN * HID);

#pragma unroll 4
    for (int i = 0; i < 16; ++i) {
        const int t = t0 + i;
        const float4* row = e4 + (size_t)t * (HID / 4);
        const float4 ea = row[lane];
        const float4 eb = row[64 + lane];
        float s = ea.x * va.x + ea.y * va.y + ea.z * va.z + ea.w * va.w
                + eb.x * vb.x + eb.y * vb.y + eb.z * vb.z + eb.w * vb.w;
#pragma unroll
        for (int off = 32; off; off >>= 1) s += __shfl_xor(s, off, 64);
        if (lane == 0) scores[b * TLEN + t] = s;
    }
}

// ---------------------------------------------------------------------------
// K3: out[b,0,t] = softmax_t(scores[b,:])   one 1024-thread block per b,
// 4 elements/thread via float4. Two block reductions (max, sum).
// ---------------------------------------------------------------------------
__global__ __launch_bounds__(1024) void softmax_kernel(const float* __restrict__ scores,
                                                       float* __restrict__ out) {
    __shared__ float redm[16];
    __shared__ float reds[16];
    const int b    = blockIdx.x;
    const int tid  = threadIdx.x;
    const int wave = tid >> 6;
    const int lane = tid & 63;

    const float4 x = ((const float4*)(scores + b * TLEN))[tid];

    // --- block max ---
    float m = fmaxf(fmaxf(x.x, x.y), fmaxf(x.z, x.w));
#pragma unroll
    for (int off = 32; off; off >>= 1) m = fmaxf(m, __shfl_xor(m, off, 64));
    if (lane == 0) redm[wave] = m;
    __syncthreads();
    if (wave == 0) {
        float t = (lane < 16) ? redm[lane] : -INFINITY;
#pragma unroll
        for (int off = 8; off; off >>= 1) t = fmaxf(t, __shfl_xor(t, off, 64));
        if (lane == 0) redm[0] = t;
    }
    __syncthreads();
    m = redm[0];

    // --- exp + block sum ---
    float4 e;
    e.x = __expf(x.x - m);
    e.y = __expf(x.y - m);
    e.z = __expf(x.z - m);
    e.w = __expf(x.w - m);
    float sum = e.x + e.y + e.z + e.w;
#pragma unroll
    for (int off = 32; off; off >>= 1) sum += __shfl_xor(sum, off, 64);
    if (lane == 0) reds[wave] = sum;
    __syncthreads();
    if (wave == 0) {
        float t = (lane < 16) ? reds[lane] : 0.f;
#pragma unroll
        for (int off = 8; off; off >>= 1) t += __shfl_xor(t, off, 64);
        if (lane == 0) reds[0] = t;
    }
    __syncthreads();
    const float inv = 1.0f / reds[0];

    float4 o4;
    o4.x = e.x * inv; o4.y = e.y * inv; o4.z = e.z * inv; o4.w = e.w * inv;
    ((float4*)(out + b * TLEN))[tid] = o4;
}

extern "C" void kernel_launch(void* const* d_in, const int* in_sizes, int n_in,
                              void* d_out, int out_size, void* d_ws, size_t ws_size,
                              hipStream_t stream) {
    const float* hidden = (const float*)d_in[0];   // [B, H]
    const float* enc    = (const float*)d_in[1];   // [B, T, H]
    const float* W      = (const float*)d_in[2];   // [H, H]
    // d_in[3] = bias — intentionally unused (cancels under softmax)
    float* out = (float*)d_out;                    // [B, 1, T]

    // workspace layout: v [B*H] floats, then scores [B*T] floats (16B aligned)
    float* v      = (float*)d_ws;
    float* scores = v + BATCH * HID;

    proj_kernel<<<dim3(BATCH), dim3(HID), 0, stream>>>(hidden, W, v);
    score_kernel<<<dim3(TLEN / 64, BATCH), dim3(256), 0, stream>>>(enc, v, scores);
    softmax_kernel<<<dim3(BATCH), dim3(1024), 0, stream>>>(scores, out);
}